// Round 14
// baseline (84.119 us; speedup 1.0000x reference)
//
#include <hip/hip_runtime.h>
#include <hip/hip_bf16.h>

#define LLEN 4096
#define BATCH 16
#define NROWS 65536   // BATCH*LLEN
#define DDIM 128
#define JDIM 256      // 2*D
#define KM1 255       // K-1
#define BR 64         // rows per block
#define TPITCH 266    // t LDS pitch in halfs (133 dwords -> odd bank stride)

typedef __attribute__((ext_vector_type(8))) _Float16 h8;
typedef __attribute__((ext_vector_type(4))) _Float16 h4;
typedef __attribute__((ext_vector_type(4))) float f4v;

__device__ __forceinline__ float clampf(float x, float lo, float hi) {
  return fminf(fmaxf(x, lo), hi);
}
__device__ __forceinline__ float tanh_fast(float x) {
  float e = __expf(2.0f * x);
  return 1.0f - 2.0f / (e + 1.0f);
}

// ---------------- kP: pack weights into MFMA frags AND X into fp16 B-frags ----------------
__global__ void kP(const float* __restrict__ X,
                   const float* __restrict__ W1, const float* __restrict__ W2,
                   _Float16* __restrict__ W1P, _Float16* __restrict__ W2P,
                   _Float16* __restrict__ Xf) {
  const int blk = blockIdx.x;
  const int tid = threadIdx.x;
  if (blk < 1024) {
    #pragma unroll
    for (int c = 0; c < 4; ++c) {
      const int chunk = blk * 1024 + c * 256 + tid;
      const int lane = chunk & 63, ks = (chunk >> 6) & 3, rt = chunk >> 8;
      const int rr = lane & 15, g = lane >> 4;
      const float* xp = X + (size_t)(rt * 16 + rr) * DDIM + ks * 32 + 8 * g;
      const float4 a = *reinterpret_cast<const float4*>(xp);
      const float4 b2 = *reinterpret_cast<const float4*>(xp + 4);
      h8 o;
      o[0]=(_Float16)a.x;  o[1]=(_Float16)a.y;  o[2]=(_Float16)a.z;  o[3]=(_Float16)a.w;
      o[4]=(_Float16)b2.x; o[5]=(_Float16)b2.y; o[6]=(_Float16)b2.z; o[7]=(_Float16)b2.w;
      *reinterpret_cast<h8*>(Xf + (size_t)chunk * 8) = o;
    }
    return;
  }
  const int T = (blk - 1024) * 256 + tid;   // 192 frags * 64 lanes
  if (T >= 192 * 64) return;
  const int frag = T >> 6, lane = T & 63;
  const int rr = lane & 15, g = lane >> 4;
  if (frag < 64) {
    const int jt = frag >> 2, ks = frag & 3;
    _Float16* base = W1P + (size_t)frag * 512 + lane * 8;
    #pragma unroll
    for (int i = 0; i < 8; ++i)
      base[i] = (_Float16)W1[(ks * 32 + 8 * g + i) * JDIM + jt * 16 + rr];
  } else {
    const int f2 = frag - 64;
    const int kt = f2 >> 3, ks = f2 & 7;
    const int k = kt * 16 + rr;
    _Float16* base = W2P + (size_t)f2 * 512 + lane * 8;
    #pragma unroll
    for (int i = 0; i < 8; ++i)
      base[i] = (k < KM1) ? (_Float16)W2[(ks * 32 + 8 * g + i) * KM1 + k] : (_Float16)0.0f;
  }
}

// ---------------- kF: fused GEMM1(tanh) -> LDS t -> GEMM2 -> exp partial sums ----------------
__launch_bounds__(512, 4)
__global__ void kF(const _Float16* __restrict__ Xf,
                   const _Float16* __restrict__ W1P, const _Float16* __restrict__ W2P,
                   const float* __restrict__ b1, const float* __restrict__ Wr,
                   const float* __restrict__ mask,
                   float* __restrict__ partE, float* __restrict__ partR) {
  __shared__ _Float16 tS[BR * TPITCH];   // 34,048 B
  __shared__ float rS[BR];

  const int tid  = threadIdx.x;
  const int lane = tid & 63, wid = tid >> 6;
  const int rr = lane & 15, g = lane >> 4;
  const int mw = wid & 3;        // M quarter (j in phase1, k in phase2)
  const int rw = wid >> 2;       // row half (32 rows)
  const int blk = blockIdx.x;
  const int b = blk >> 6;        // 64 blocks per batch
  const int r_base = blk * BR;

  f4v acc[4][2];
  #pragma unroll
  for (int m = 0; m < 4; ++m)
    #pragma unroll
    for (int n = 0; n < 2; ++n) { acc[m][n][0]=0.f; acc[m][n][1]=0.f; acc[m][n][2]=0.f; acc[m][n][3]=0.f; }
  float rp[2] = {0.f, 0.f};

  // ---- issue ALL phase-1 X fragments (8 x 16B loads in flight) ----
  h8 xf[4][2];
  #pragma unroll
  for (int ks = 0; ks < 4; ++ks)
    #pragma unroll
    for (int nf = 0; nf < 2; ++nf) {
      const int rt = blk * 4 + rw * 2 + nf;
      xf[ks][nf] = *reinterpret_cast<const h8*>(Xf + ((size_t)(rt * 4 + ks) * 64 + lane) * 8);
    }

  // ---- phase 1: t = tanh(X@W1+b1), M=j(256), N=rows(64), K=d(128). No barriers. ----
  h8 Wc[4], Wn[4];
  #pragma unroll
  for (int mf = 0; mf < 4; ++mf)
    Wc[mf] = *reinterpret_cast<const h8*>(W1P + (size_t)((mw * 4 + mf) * 4) * 512 + lane * 8);
  #pragma unroll
  for (int ks = 0; ks < 4; ++ks) {
    if (ks < 3) {
      #pragma unroll
      for (int mf = 0; mf < 4; ++mf)
        Wn[mf] = *reinterpret_cast<const h8*>(W1P + (size_t)((mw * 4 + mf) * 4 + ks + 1) * 512 + lane * 8);
    }
    if (mw == 0) {
      const float4 w0 = *reinterpret_cast<const float4*>(Wr + ks * 32 + 8 * g);
      const float4 w1 = *reinterpret_cast<const float4*>(Wr + ks * 32 + 8 * g + 4);
      const float wr[8] = {w0.x, w0.y, w0.z, w0.w, w1.x, w1.y, w1.z, w1.w};
      #pragma unroll
      for (int nf = 0; nf < 2; ++nf)
        #pragma unroll
        for (int i = 0; i < 8; ++i)
          rp[nf] += (float)xf[ks][nf][i] * wr[i];   // v_fma_mix
    }
    __builtin_amdgcn_s_setprio(1);
    #pragma unroll
    for (int mf = 0; mf < 4; ++mf)
      #pragma unroll
      for (int nf = 0; nf < 2; ++nf)
        acc[mf][nf] = __builtin_amdgcn_mfma_f32_16x16x32_f16(Wc[mf], xf[ks][nf], acc[mf][nf], 0, 0, 0);
    __builtin_amdgcn_s_setprio(0);
    if (ks < 3) {
      #pragma unroll
      for (int mf = 0; mf < 4; ++mf) Wc[mf] = Wn[mf];
    }
  }

  // hoist phase-2 W2 frags depth-2
  #pragma unroll
  for (int mf = 0; mf < 4; ++mf) {
    Wc[mf] = *reinterpret_cast<const h8*>(W2P + (size_t)((mw * 4 + mf) * 8) * 512 + lane * 8);
    Wn[mf] = *reinterpret_cast<const h8*>(W2P + (size_t)((mw * 4 + mf) * 8 + 1) * 512 + lane * 8);
  }

  // epilogue 1: bias + tanh -> fp16 tS; fused r-dot -> rS
  #pragma unroll
  for (int mf = 0; mf < 4; ++mf) {
    const int j0 = (mw * 4 + mf) * 16 + 4 * g;
    const float4 bv = *reinterpret_cast<const float4*>(b1 + j0);
    const float bva[4] = {bv.x, bv.y, bv.z, bv.w};
    #pragma unroll
    for (int nf = 0; nf < 2; ++nf) {
      const int rl = rw * 32 + nf * 16 + rr;
      h4 o;
      #pragma unroll
      for (int reg = 0; reg < 4; ++reg)
        o[reg] = (_Float16)tanh_fast(acc[mf][nf][reg] + bva[reg]);
      *reinterpret_cast<h4*>(&tS[rl * TPITCH + j0]) = o;
    }
  }
  if (mw == 0) {
    #pragma unroll
    for (int nf = 0; nf < 2; ++nf) {
      rp[nf] += __shfl_xor(rp[nf], 16, 64);
      rp[nf] += __shfl_xor(rp[nf], 32, 64);
    }
    if (g == 0) {
      #pragma unroll
      for (int nf = 0; nf < 2; ++nf) rS[rw * 32 + nf * 16 + rr] = rp[nf];
    }
  }
  // re-zero accumulators for phase 2
  #pragma unroll
  for (int m = 0; m < 4; ++m)
    #pragma unroll
    for (int n = 0; n < 2; ++n) { acc[m][n][0]=0.f; acc[m][n][1]=0.f; acc[m][n][2]=0.f; acc[m][n][3]=0.f; }
  __syncthreads();   // the only barrier

  // hoist epilogue-2 scalars
  float mv[2], rv[2];
  #pragma unroll
  for (int nf = 0; nf < 2; ++nf) {
    const int rl = rw * 32 + nf * 16 + rr;
    mv[nf] = mask[r_base + rl];
    rv[nf] = rS[rl];
  }

  // ---- phase 2: logits = t@W2, M=k(256), N=rows(64), K=j(256). W2 depth-2, Bt depth-1. ----
  h8 Btc[2], Btn[2];
  #pragma unroll
  for (int nf = 0; nf < 2; ++nf) {
    const int rl = rw * 32 + nf * 16 + rr;
    Btc[nf] = *reinterpret_cast<const h8*>(&tS[rl * TPITCH + 8 * g]);
  }
  #pragma unroll
  for (int ks = 0; ks < 8; ++ks) {
    h8 Wn2[4];
    if (ks < 6) {
      #pragma unroll
      for (int mf = 0; mf < 4; ++mf)
        Wn2[mf] = *reinterpret_cast<const h8*>(W2P + (size_t)((mw * 4 + mf) * 8 + ks + 2) * 512 + lane * 8);
    }
    if (ks < 7) {
      #pragma unroll
      for (int nf = 0; nf < 2; ++nf) {
        const int rl = rw * 32 + nf * 16 + rr;
        Btn[nf] = *reinterpret_cast<const h8*>(&tS[rl * TPITCH + (ks + 1) * 32 + 8 * g]);
      }
    }
    __builtin_amdgcn_s_setprio(1);
    #pragma unroll
    for (int mf = 0; mf < 4; ++mf)
      #pragma unroll
      for (int nf = 0; nf < 2; ++nf)
        acc[mf][nf] = __builtin_amdgcn_mfma_f32_16x16x32_f16(Wc[mf], Btc[nf], acc[mf][nf], 0, 0, 0);
    __builtin_amdgcn_s_setprio(0);
    #pragma unroll
    for (int mf = 0; mf < 4; ++mf) Wc[mf] = Wn[mf];
    if (ks < 6) {
      #pragma unroll
      for (int mf = 0; mf < 4; ++mf) Wn[mf] = Wn2[mf];
    }
    if (ks < 7) {
      #pragma unroll
      for (int nf = 0; nf < 2; ++nf) Btc[nf] = Btn[nf];
    }
  }

  // epilogue 2: masked exp; per-k sums; partial write
  float sE[4][4], sR[4][4];
  #pragma unroll
  for (int mf = 0; mf < 4; ++mf)
    #pragma unroll
    for (int reg = 0; reg < 4; ++reg) { sE[mf][reg] = 0.f; sR[mf][reg] = 0.f; }
  #pragma unroll
  for (int nf = 0; nf < 2; ++nf) {
    const float addm = (1.0f - mv[nf]) * (-1e30f);
    #pragma unroll
    for (int mf = 0; mf < 4; ++mf)
      #pragma unroll
      for (int reg = 0; reg < 4; ++reg) {
        const float e = __expf(mv[nf] * acc[mf][nf][reg] + addm);
        sE[mf][reg] += e;
        sR[mf][reg] += e * rv[nf];
      }
  }
  #pragma unroll
  for (int off = 1; off < 16; off <<= 1)
    #pragma unroll
    for (int mf = 0; mf < 4; ++mf)
      #pragma unroll
      for (int reg = 0; reg < 4; ++reg) {
        sE[mf][reg] += __shfl_xor(sE[mf][reg], off, 64);
        sR[mf][reg] += __shfl_xor(sR[mf][reg], off, 64);
      }
  if (rr == 0) {
    const int s = (blk & 63) * 2 + rw;            // 0..127 within batch
    float* pE = partE + (size_t)s * 4096 + b * 256;
    float* pR = partR + (size_t)s * 4096 + b * 256;
    #pragma unroll
    for (int mf = 0; mf < 4; ++mf)
      #pragma unroll
      for (int reg = 0; reg < 4; ++reg) {
        const int k = (mw * 4 + mf) * 16 + 4 * g + reg;
        pE[k] = sE[mf][reg];
        pR[k] = sR[mf][reg];
      }
  }
}

// ---------------- kC: coalesced partial reduction + softmax/cumsum/params (one kernel) ----------------
// grid 16, 256 thr. Reduction: 4 kq rounds, lanes span k (coalesced), LDS combine -> muS.
__global__ void kC(const float* __restrict__ partE, const float* __restrict__ partR,
                   const float* __restrict__ br, float* __restrict__ params) {
  __shared__ float rE[4][64];
  __shared__ float rR[4][64];
  __shared__ float muS[256];
  __shared__ float red[256];
  __shared__ float sm[256];
  const int b = blockIdx.x;
  const int tid = threadIdx.x;
  const int kl = tid & 63, sq = tid >> 6;
  #pragma unroll
  for (int kq = 0; kq < 4; ++kq) {
    const size_t idx = (size_t)b * 256 + kq * 64 + kl;
    float e = 0.0f, r = 0.0f;
    #pragma unroll 8
    for (int i = 0; i < 32; ++i) {
      const int s = sq * 32 + i;
      e += partE[(size_t)s * 4096 + idx];
      r += partR[(size_t)s * 4096 + idx];
    }
    rE[sq][kl] = e; rR[sq][kl] = r;
    __syncthreads();
    if (tid < 64) {
      const float esum = rE[0][tid] + rE[1][tid] + rE[2][tid] + rE[3][tid];
      const float rsum = rR[0][tid] + rR[1][tid] + rR[2][tid] + rR[3][tid];
      muS[kq * 64 + tid] = rsum / esum;
    }
    __syncthreads();
  }
  const int k = tid;
  float v = 0.0f;
  if (k > 0) v = muS[k - 1] + br[0];
  red[k] = v; __syncthreads();
  #pragma unroll
  for (int off = 128; off > 0; off >>= 1) {
    if (k < off) red[k] = fmaxf(red[k], red[k + off]);
    __syncthreads();
  }
  const float vmax = red[0];
  __syncthreads();
  const float e = expf(v - vmax);
  red[k] = e; __syncthreads();
  #pragma unroll
  for (int off = 128; off > 0; off >>= 1) {
    if (k < off) red[k] += red[k + off];
    __syncthreads();
  }
  const float tot = red[0];
  __syncthreads();
  sm[k] = e / tot; __syncthreads();
  for (int off = 1; off < 256; off <<= 1) {
    const float add = (k >= off) ? sm[k - off] : 0.0f;
    __syncthreads();
    sm[k] += add;
    __syncthreads();
  }
  if (k < KM1) {
    const float m  = clampf(sm[k], 1e-4f, 0.9999f);
    const float a  = clampf(m - 0.0625f, 0.0f, 0.875f);
    const float bb = clampf(a + 0.125f, 0.125f, 1.0f);
    const float ba = bb - a, ma = m - a, bm = bb - m;
    float* p = params + ((size_t)b * KM1 + k) * 8;
    *reinterpret_cast<float4*>(p)     = make_float4(m, a, bb, ma / ba);
    *reinterpret_cast<float4*>(p + 4) = make_float4(1.0f / ma, bm / ba, 1.0f / bm, 0.0f);
  }
}

// ---------------- kD: gamma_scaled + almat, 64 l per block, 4-way split-k chains ----------------
__launch_bounds__(256)
__global__ void kD(const float* __restrict__ params, float* __restrict__ gamma,
                   float* __restrict__ almat) {
  __shared__ float P[KM1][8];
  __shared__ float red[4][64];
  __shared__ float gl[64];
  const int lc = blockIdx.x, b = blockIdx.y;   // lc < 64
  const int tid = threadIdx.x;
  if (tid < KM1) {
    const float* p = params + ((size_t)b * KM1 + tid) * 8;
    *reinterpret_cast<float4*>(&P[tid][0]) = *reinterpret_cast<const float4*>(p);
    *reinterpret_cast<float4*>(&P[tid][4]) = *reinterpret_cast<const float4*>(p + 4);
  }
  __syncthreads();
  const int li = tid & 63, lq = tid >> 6;
  const int l = lc * 64 + li;
  const float x = (float)l * (1.0f / 4095.0f);
  float gacc = 0.0f;
  const int k0 = lq * 64;
  const int k1 = (k0 + 64 < KM1) ? (k0 + 64) : KM1;
  for (int k = k0; k < k1; ++k) {
    const float m = P[k][0], a = P[k][1], bb = P[k][2], cL = P[k][3];
    const float iMA = P[k][4], cR = P[k][5], iBM = P[k][6];
    float u = clampf((x - a) * iMA, 0.0f, 1.0f);
    u = u * u; u = u * u; u = u * u; u = u * u;
    float w = clampf((bb - x) * iBM, 0.0f, 1.0f);
    w = w * w; w = w * w; w = w * w; w = w * w;
    const float left  = cL * u;
    const float right = 1.0f - cR * w;
    gacc += (x <= m) ? left : right;
  }
  red[lq][li] = gacc;
  __syncthreads();
  if (tid < 64) {
    const float tot = red[0][tid] + red[1][tid] + red[2][tid] + red[3][tid];
    gl[tid] = tot;
    gamma[(size_t)b * LLEN + lc * 64 + tid] = tot;
  }
  __syncthreads();
  const int kg = (tid & 63) * 4;
  const int i0 = tid >> 6;
  const float kg0 = (float)kg;
  const size_t base = ((size_t)b * LLEN + (size_t)lc * 64) * 256;
  for (int s = 0; s < 16; ++s) {
    const int i = s * 4 + i0;
    const float gv = gl[i];
    float4 v;
    v.x = fmaxf(1.0f - fabsf(gv - kg0), 0.0f);
    v.y = fmaxf(1.0f - fabsf(gv - (kg0 + 1.0f)), 0.0f);
    v.z = fmaxf(1.0f - fabsf(gv - (kg0 + 2.0f)), 0.0f);
    v.w = fmaxf(1.0f - fabsf(gv - (kg0 + 3.0f)), 0.0f);
    *reinterpret_cast<float4*>(&almat[base + (size_t)i * 256 + kg]) = v;
  }
}

extern "C" void kernel_launch(void* const* d_in, const int* in_sizes, int n_in,
                              void* d_out, int out_size, void* d_ws, size_t ws_size,
                              hipStream_t stream) {
  const float* X    = (const float*)d_in[0];
  const float* mask = (const float*)d_in[1];
  const float* W1   = (const float*)d_in[2];
  const float* b1   = (const float*)d_in[3];
  const float* W2   = (const float*)d_in[4];
  const float* Wr   = (const float*)d_in[5];
  const float* br   = (const float*)d_in[6];
  float* out   = (float*)d_out;
  float* gamma = out;
  float* almat = out + NROWS;
  // aliased scratch inside almat region (fully overwritten by kD afterwards):
  float* partE = almat;                               // [128][4096] f32 = 2 MB
  float* partR = almat + (size_t)128 * 4096;          // 2 MB
  _Float16* Xf = (_Float16*)(almat + (size_t)2 * 1024 * 1024);  // 16.8 MB at +8 MB offset
  // workspace
  float* params = (float*)d_ws;                                  // [16][255][8]
  _Float16* W1P = (_Float16*)(params + (size_t)BATCH * KM1 * 8); // 64 frags * 512 halfs
  _Float16* W2P = W1P + 64 * 512;                                // 128 frags * 512 halfs

  kP<<<1072, 256, 0, stream>>>(X, W1, W2, W1P, W2P, Xf);
  kF<<<NROWS / BR, 512, 0, stream>>>(Xf, W1P, W2P, b1, Wr, mask, partE, partR);
  kC<<<BATCH, 256, 0, stream>>>(partE, partR, br, params);
  kD<<<dim3(64, BATCH), 256, 0, stream>>>(params, gamma, almat);
}

// Round 15
// 75.017 us; speedup vs baseline: 1.1213x; 1.1213x over previous
//
#include <hip/hip_runtime.h>
#include <hip/hip_bf16.h>

#define LLEN 4096
#define BATCH 16
#define NROWS 65536   // BATCH*LLEN
#define DDIM 128
#define JDIM 256      // 2*D
#define KM1 255       // K-1
#define BR 64         // rows per block
#define TPITCH 266    // t LDS pitch in halfs (133 dwords -> odd bank stride)

typedef __attribute__((ext_vector_type(8))) _Float16 h8;
typedef __attribute__((ext_vector_type(4))) _Float16 h4;
typedef __attribute__((ext_vector_type(4))) float f4v;

__device__ __forceinline__ float clampf(float x, float lo, float hi) {
  return fminf(fmaxf(x, lo), hi);
}
__device__ __forceinline__ float tanh_fast(float x) {
  float e = __expf(2.0f * x);
  return 1.0f - 2.0f / (e + 1.0f);
}

// ---------------- kP: pack weights into MFMA frags AND X into fp16 B-frags ----------------
__global__ void kP(const float* __restrict__ X,
                   const float* __restrict__ W1, const float* __restrict__ W2,
                   _Float16* __restrict__ W1P, _Float16* __restrict__ W2P,
                   _Float16* __restrict__ Xf) {
  const int blk = blockIdx.x;
  const int tid = threadIdx.x;
  if (blk < 1024) {
    #pragma unroll
    for (int c = 0; c < 4; ++c) {
      const int chunk = blk * 1024 + c * 256 + tid;
      const int lane = chunk & 63, ks = (chunk >> 6) & 3, rt = chunk >> 8;
      const int rr = lane & 15, g = lane >> 4;
      const float* xp = X + (size_t)(rt * 16 + rr) * DDIM + ks * 32 + 8 * g;
      const float4 a = *reinterpret_cast<const float4*>(xp);
      const float4 b2 = *reinterpret_cast<const float4*>(xp + 4);
      h8 o;
      o[0]=(_Float16)a.x;  o[1]=(_Float16)a.y;  o[2]=(_Float16)a.z;  o[3]=(_Float16)a.w;
      o[4]=(_Float16)b2.x; o[5]=(_Float16)b2.y; o[6]=(_Float16)b2.z; o[7]=(_Float16)b2.w;
      *reinterpret_cast<h8*>(Xf + (size_t)chunk * 8) = o;
    }
    return;
  }
  const int T = (blk - 1024) * 256 + tid;   // 192 frags * 64 lanes
  if (T >= 192 * 64) return;
  const int frag = T >> 6, lane = T & 63;
  const int rr = lane & 15, g = lane >> 4;
  if (frag < 64) {
    const int jt = frag >> 2, ks = frag & 3;
    _Float16* base = W1P + (size_t)frag * 512 + lane * 8;
    #pragma unroll
    for (int i = 0; i < 8; ++i)
      base[i] = (_Float16)W1[(ks * 32 + 8 * g + i) * JDIM + jt * 16 + rr];
  } else {
    const int f2 = frag - 64;
    const int kt = f2 >> 3, ks = f2 & 7;
    const int k = kt * 16 + rr;
    _Float16* base = W2P + (size_t)f2 * 512 + lane * 8;
    #pragma unroll
    for (int i = 0; i < 8; ++i)
      base[i] = (k < KM1) ? (_Float16)W2[(ks * 32 + 8 * g + i) * KM1 + k] : (_Float16)0.0f;
  }
}

// ---------------- kF: fused GEMM1(tanh) -> LDS t -> GEMM2 -> exp partial sums ----------------
__launch_bounds__(512, 4)
__global__ void kF(const _Float16* __restrict__ Xf,
                   const _Float16* __restrict__ W1P, const _Float16* __restrict__ W2P,
                   const float* __restrict__ b1, const float* __restrict__ Wr,
                   const float* __restrict__ mask,
                   float* __restrict__ partE, float* __restrict__ partR) {
  __shared__ _Float16 tS[BR * TPITCH];   // 34,048 B
  __shared__ float rS[BR];

  const int tid  = threadIdx.x;
  const int lane = tid & 63, wid = tid >> 6;
  const int rr = lane & 15, g = lane >> 4;
  const int mw = wid & 3;        // M quarter (j in phase1, k in phase2)
  const int rw = wid >> 2;       // row half (32 rows)
  const int blk = blockIdx.x;
  const int b = blk >> 6;        // 64 blocks per batch
  const int r_base = blk * BR;

  f4v acc[4][2];
  #pragma unroll
  for (int m = 0; m < 4; ++m)
    #pragma unroll
    for (int n = 0; n < 2; ++n) { acc[m][n][0]=0.f; acc[m][n][1]=0.f; acc[m][n][2]=0.f; acc[m][n][3]=0.f; }
  float rp[2] = {0.f, 0.f};

  // ---- issue ALL phase-1 X fragments (8 x 16B loads in flight) ----
  h8 xf[4][2];
  #pragma unroll
  for (int ks = 0; ks < 4; ++ks)
    #pragma unroll
    for (int nf = 0; nf < 2; ++nf) {
      const int rt = blk * 4 + rw * 2 + nf;
      xf[ks][nf] = *reinterpret_cast<const h8*>(Xf + ((size_t)(rt * 4 + ks) * 64 + lane) * 8);
    }

  // ---- phase 1: t = tanh(X@W1+b1), M=j(256), N=rows(64), K=d(128). No barriers. ----
  h8 Wc[4], Wn[4];
  #pragma unroll
  for (int mf = 0; mf < 4; ++mf)
    Wc[mf] = *reinterpret_cast<const h8*>(W1P + (size_t)((mw * 4 + mf) * 4) * 512 + lane * 8);
  #pragma unroll
  for (int ks = 0; ks < 4; ++ks) {
    if (ks < 3) {
      #pragma unroll
      for (int mf = 0; mf < 4; ++mf)
        Wn[mf] = *reinterpret_cast<const h8*>(W1P + (size_t)((mw * 4 + mf) * 4 + ks + 1) * 512 + lane * 8);
    }
    if (mw == 0) {
      const float4 w0 = *reinterpret_cast<const float4*>(Wr + ks * 32 + 8 * g);
      const float4 w1 = *reinterpret_cast<const float4*>(Wr + ks * 32 + 8 * g + 4);
      const float wr[8] = {w0.x, w0.y, w0.z, w0.w, w1.x, w1.y, w1.z, w1.w};
      #pragma unroll
      for (int nf = 0; nf < 2; ++nf)
        #pragma unroll
        for (int i = 0; i < 8; ++i)
          rp[nf] += (float)xf[ks][nf][i] * wr[i];   // v_fma_mix
    }
    #pragma unroll
    for (int mf = 0; mf < 4; ++mf)
      #pragma unroll
      for (int nf = 0; nf < 2; ++nf)
        acc[mf][nf] = __builtin_amdgcn_mfma_f32_16x16x32_f16(Wc[mf], xf[ks][nf], acc[mf][nf], 0, 0, 0);
    if (ks < 3) {
      #pragma unroll
      for (int mf = 0; mf < 4; ++mf) Wc[mf] = Wn[mf];
    }
  }

  // hoist phase-2 W2 frags depth-2
  #pragma unroll
  for (int mf = 0; mf < 4; ++mf) {
    Wc[mf] = *reinterpret_cast<const h8*>(W2P + (size_t)((mw * 4 + mf) * 8) * 512 + lane * 8);
    Wn[mf] = *reinterpret_cast<const h8*>(W2P + (size_t)((mw * 4 + mf) * 8 + 1) * 512 + lane * 8);
  }

  // epilogue 1: bias + tanh -> fp16 tS; fused r-dot -> rS
  #pragma unroll
  for (int mf = 0; mf < 4; ++mf) {
    const int j0 = (mw * 4 + mf) * 16 + 4 * g;
    const float4 bv = *reinterpret_cast<const float4*>(b1 + j0);
    const float bva[4] = {bv.x, bv.y, bv.z, bv.w};
    #pragma unroll
    for (int nf = 0; nf < 2; ++nf) {
      const int rl = rw * 32 + nf * 16 + rr;
      h4 o;
      #pragma unroll
      for (int reg = 0; reg < 4; ++reg)
        o[reg] = (_Float16)tanh_fast(acc[mf][nf][reg] + bva[reg]);
      *reinterpret_cast<h4*>(&tS[rl * TPITCH + j0]) = o;
    }
  }
  if (mw == 0) {
    #pragma unroll
    for (int nf = 0; nf < 2; ++nf) {
      rp[nf] += __shfl_xor(rp[nf], 16, 64);
      rp[nf] += __shfl_xor(rp[nf], 32, 64);
    }
    if (g == 0) {
      #pragma unroll
      for (int nf = 0; nf < 2; ++nf) rS[rw * 32 + nf * 16 + rr] = rp[nf];
    }
  }
  // re-zero accumulators for phase 2
  #pragma unroll
  for (int m = 0; m < 4; ++m)
    #pragma unroll
    for (int n = 0; n < 2; ++n) { acc[m][n][0]=0.f; acc[m][n][1]=0.f; acc[m][n][2]=0.f; acc[m][n][3]=0.f; }
  __syncthreads();   // the only barrier

  // hoist epilogue-2 scalars
  float mv[2], rv[2];
  #pragma unroll
  for (int nf = 0; nf < 2; ++nf) {
    const int rl = rw * 32 + nf * 16 + rr;
    mv[nf] = mask[r_base + rl];
    rv[nf] = rS[rl];
  }

  // ---- phase 2: logits = t@W2, M=k(256), N=rows(64), K=j(256). W2 depth-2, Bt depth-1. ----
  h8 Btc[2], Btn[2];
  #pragma unroll
  for (int nf = 0; nf < 2; ++nf) {
    const int rl = rw * 32 + nf * 16 + rr;
    Btc[nf] = *reinterpret_cast<const h8*>(&tS[rl * TPITCH + 8 * g]);
  }
  #pragma unroll
  for (int ks = 0; ks < 8; ++ks) {
    h8 Wn2[4];
    if (ks < 6) {
      #pragma unroll
      for (int mf = 0; mf < 4; ++mf)
        Wn2[mf] = *reinterpret_cast<const h8*>(W2P + (size_t)((mw * 4 + mf) * 8 + ks + 2) * 512 + lane * 8);
    }
    if (ks < 7) {
      #pragma unroll
      for (int nf = 0; nf < 2; ++nf) {
        const int rl = rw * 32 + nf * 16 + rr;
        Btn[nf] = *reinterpret_cast<const h8*>(&tS[rl * TPITCH + (ks + 1) * 32 + 8 * g]);
      }
    }
    #pragma unroll
    for (int mf = 0; mf < 4; ++mf)
      #pragma unroll
      for (int nf = 0; nf < 2; ++nf)
        acc[mf][nf] = __builtin_amdgcn_mfma_f32_16x16x32_f16(Wc[mf], Btc[nf], acc[mf][nf], 0, 0, 0);
    #pragma unroll
    for (int mf = 0; mf < 4; ++mf) Wc[mf] = Wn[mf];
    if (ks < 6) {
      #pragma unroll
      for (int mf = 0; mf < 4; ++mf) Wn[mf] = Wn2[mf];
    }
    if (ks < 7) {
      #pragma unroll
      for (int nf = 0; nf < 2; ++nf) Btc[nf] = Btn[nf];
    }
  }

  // epilogue 2: masked exp; per-k sums; partial write
  float sE[4][4], sR[4][4];
  #pragma unroll
  for (int mf = 0; mf < 4; ++mf)
    #pragma unroll
    for (int reg = 0; reg < 4; ++reg) { sE[mf][reg] = 0.f; sR[mf][reg] = 0.f; }
  #pragma unroll
  for (int nf = 0; nf < 2; ++nf) {
    const float addm = (1.0f - mv[nf]) * (-1e30f);
    #pragma unroll
    for (int mf = 0; mf < 4; ++mf)
      #pragma unroll
      for (int reg = 0; reg < 4; ++reg) {
        const float e = __expf(mv[nf] * acc[mf][nf][reg] + addm);
        sE[mf][reg] += e;
        sR[mf][reg] += e * rv[nf];
      }
  }
  #pragma unroll
  for (int off = 1; off < 16; off <<= 1)
    #pragma unroll
    for (int mf = 0; mf < 4; ++mf)
      #pragma unroll
      for (int reg = 0; reg < 4; ++reg) {
        sE[mf][reg] += __shfl_xor(sE[mf][reg], off, 64);
        sR[mf][reg] += __shfl_xor(sR[mf][reg], off, 64);
      }
  if (rr == 0) {
    const int s = (blk & 63) * 2 + rw;            // 0..127 within batch
    float* pE = partE + (size_t)s * 4096 + b * 256;
    float* pR = partR + (size_t)s * 4096 + b * 256;
    #pragma unroll
    for (int mf = 0; mf < 4; ++mf)
      #pragma unroll
      for (int reg = 0; reg < 4; ++reg) {
        const int k = (mw * 4 + mf) * 16 + 4 * g + reg;
        pE[k] = sE[mf][reg];
        pR[k] = sR[mf][reg];
      }
  }
}

// ---------------- kC1: parallel partial reduction -> mu[b][k] ----------------
// grid (4, 16), 256 thr. lanes span k (coalesced); 4 s-groups x 32 iters; LDS combine.
__global__ void kC1(const float* __restrict__ partE, const float* __restrict__ partR,
                    float* __restrict__ mu) {
  __shared__ float rE[4][64];
  __shared__ float rR[4][64];
  const int kq = blockIdx.x, b = blockIdx.y;
  const int tid = threadIdx.x;
  const int kl = tid & 63, sq = tid >> 6;
  const size_t idx = (size_t)b * 256 + kq * 64 + kl;
  float e = 0.0f, r = 0.0f;
  #pragma unroll 8
  for (int i = 0; i < 32; ++i) {
    const int s = sq * 32 + i;
    e += partE[(size_t)s * 4096 + idx];
    r += partR[(size_t)s * 4096 + idx];
  }
  rE[sq][kl] = e; rR[sq][kl] = r;
  __syncthreads();
  if (tid < 64) {
    const float esum = rE[0][tid] + rE[1][tid] + rE[2][tid] + rE[3][tid];
    const float rsum = rR[0][tid] + rR[1][tid] + rR[2][tid] + rR[3][tid];
    mu[b * 256 + kq * 64 + tid] = rsum / esum;
  }
}

// ---------------- kC2: mu -> softmax -> cumsum -> cdf params ----------------
__global__ void kC2(const float* __restrict__ mu, const float* __restrict__ br,
                    float* __restrict__ params) {
  __shared__ float red[256];
  __shared__ float sm[256];
  const int b = blockIdx.x;
  const int k = threadIdx.x;
  float v = 0.0f;
  if (k > 0) v = mu[b * 256 + (k - 1)] + br[0];
  red[k] = v; __syncthreads();
  #pragma unroll
  for (int off = 128; off > 0; off >>= 1) {
    if (k < off) red[k] = fmaxf(red[k], red[k + off]);
    __syncthreads();
  }
  const float vmax = red[0];
  __syncthreads();
  const float e = expf(v - vmax);
  red[k] = e; __syncthreads();
  #pragma unroll
  for (int off = 128; off > 0; off >>= 1) {
    if (k < off) red[k] += red[k + off];
    __syncthreads();
  }
  const float tot = red[0];
  __syncthreads();
  sm[k] = e / tot; __syncthreads();
  for (int off = 1; off < 256; off <<= 1) {
    const float add = (k >= off) ? sm[k - off] : 0.0f;
    __syncthreads();
    sm[k] += add;
    __syncthreads();
  }
  if (k < KM1) {
    const float m  = clampf(sm[k], 1e-4f, 0.9999f);
    const float a  = clampf(m - 0.0625f, 0.0f, 0.875f);
    const float bb = clampf(a + 0.125f, 0.125f, 1.0f);
    const float ba = bb - a, ma = m - a, bm = bb - m;
    float* p = params + ((size_t)b * KM1 + k) * 8;
    *reinterpret_cast<float4*>(p)     = make_float4(m, a, bb, ma / ba);
    *reinterpret_cast<float4*>(p + 4) = make_float4(1.0f / ma, bm / ba, 1.0f / bm, 0.0f);
  }
}

// ---------------- kD: gamma_scaled + almat, 64 l per block, 4-way split-k chains ----------------
__launch_bounds__(256)
__global__ void kD(const float* __restrict__ params, float* __restrict__ gamma,
                   float* __restrict__ almat) {
  __shared__ float P[KM1][8];
  __shared__ float red[4][64];
  __shared__ float gl[64];
  const int lc = blockIdx.x, b = blockIdx.y;   // lc < 64
  const int tid = threadIdx.x;
  if (tid < KM1) {
    const float* p = params + ((size_t)b * KM1 + tid) * 8;
    *reinterpret_cast<float4*>(&P[tid][0]) = *reinterpret_cast<const float4*>(p);
    *reinterpret_cast<float4*>(&P[tid][4]) = *reinterpret_cast<const float4*>(p + 4);
  }
  __syncthreads();
  const int li = tid & 63, lq = tid >> 6;
  const int l = lc * 64 + li;
  const float x = (float)l * (1.0f / 4095.0f);
  float gacc = 0.0f;
  const int k0 = lq * 64;
  const int k1 = (k0 + 64 < KM1) ? (k0 + 64) : KM1;
  for (int k = k0; k < k1; ++k) {
    const float m = P[k][0], a = P[k][1], bb = P[k][2], cL = P[k][3];
    const float iMA = P[k][4], cR = P[k][5], iBM = P[k][6];
    float u = clampf((x - a) * iMA, 0.0f, 1.0f);
    u = u * u; u = u * u; u = u * u; u = u * u;
    float w = clampf((bb - x) * iBM, 0.0f, 1.0f);
    w = w * w; w = w * w; w = w * w; w = w * w;
    const float left  = cL * u;
    const float right = 1.0f - cR * w;
    gacc += (x <= m) ? left : right;
  }
  red[lq][li] = gacc;
  __syncthreads();
  if (tid < 64) {
    const float tot = red[0][tid] + red[1][tid] + red[2][tid] + red[3][tid];
    gl[tid] = tot;
    gamma[(size_t)b * LLEN + lc * 64 + tid] = tot;
  }
  __syncthreads();
  const int kg = (tid & 63) * 4;
  const int i0 = tid >> 6;
  const float kg0 = (float)kg;
  const size_t base = ((size_t)b * LLEN + (size_t)lc * 64) * 256;
  for (int s = 0; s < 16; ++s) {
    const int i = s * 4 + i0;
    const float gv = gl[i];
    float4 v;
    v.x = fmaxf(1.0f - fabsf(gv - kg0), 0.0f);
    v.y = fmaxf(1.0f - fabsf(gv - (kg0 + 1.0f)), 0.0f);
    v.z = fmaxf(1.0f - fabsf(gv - (kg0 + 2.0f)), 0.0f);
    v.w = fmaxf(1.0f - fabsf(gv - (kg0 + 3.0f)), 0.0f);
    *reinterpret_cast<float4*>(&almat[base + (size_t)i * 256 + kg]) = v;
  }
}

extern "C" void kernel_launch(void* const* d_in, const int* in_sizes, int n_in,
                              void* d_out, int out_size, void* d_ws, size_t ws_size,
                              hipStream_t stream) {
  const float* X    = (const float*)d_in[0];
  const float* mask = (const float*)d_in[1];
  const float* W1   = (const float*)d_in[2];
  const float* b1   = (const float*)d_in[3];
  const float* W2   = (const float*)d_in[4];
  const float* Wr   = (const float*)d_in[5];
  const float* br   = (const float*)d_in[6];
  float* out   = (float*)d_out;
  float* gamma = out;
  float* almat = out + NROWS;
  // aliased scratch inside almat region (fully overwritten by kD afterwards):
  float* partE = almat;                               // [128][4096] f32 = 2 MB
  float* partR = almat + (size_t)128 * 4096;          // 2 MB
  _Float16* Xf = (_Float16*)(almat + (size_t)2 * 1024 * 1024);  // 16.8 MB at +8 MB offset
  // workspace
  float* params = (float*)d_ws;                                  // [16][255][8]
  _Float16* W1P = (_Float16*)(params + (size_t)BATCH * KM1 * 8); // 64 frags * 512 halfs
  _Float16* W2P = W1P + 64 * 512;                                // 128 frags * 512 halfs
  float* mu = (float*)(W2P + 128 * 512);                         // [16][256]

  kP<<<1072, 256, 0, stream>>>(X, W1, W2, W1P, W2P, Xf);
  kF<<<NROWS / BR, 512, 0, stream>>>(Xf, W1P, W2P, b1, Wr, mask, partE, partR);
  kC1<<<dim3(4, BATCH), 256, 0, stream>>>(partE, partR, mu);
  kC2<<<BATCH, 256, 0, stream>>>(mu, br, params);
  kD<<<dim3(64, BATCH), 256, 0, stream>>>(params, gamma, almat);
}